// Round 1
// baseline (156.148 us; speedup 1.0000x reference)
//
#include <hip/hip_runtime.h>
#include <math.h>

// PointConv: N_IN=N_OUT=100000, E=1600000, C_IN=1, C_MID=64, C_OUT=64, POS_DIM=3
//
// Structure:
//   k_lower_bound: CSR row offsets for sorted out_index (binary search per node)
//   k_main: one wave per output node.
//     - lane j owns output channel j (0..63)
//     - edges processed 4 at a time; 16-lane subgroup g computes edge (base+g)'s
//       h1[16] (pos_local @ W1, celu)
//     - stage 2: h1 broadcast via v_readlane (compile-time lanes), 16 FMA vs
//       per-lane W2 column in registers, celu, scale by x_in[src]/deg, accumulate
//     - epilogue fused: out[o][j] = sum_c agg_c * W3[c][j] + b3[j], agg broadcast
//       via readlane, W3 staged in LDS once per block. nan_to_num applied.

__device__ __forceinline__ float celu1(float x) {
    return x > 0.0f ? x : (__expf(x) - 1.0f);
}

__device__ __forceinline__ float bcastf(float v, int l) {
    return __int_as_float(__builtin_amdgcn_readlane(__float_as_int(v), l));
}

__global__ void k_lower_bound(const int* __restrict__ oi, int* __restrict__ start,
                              int n_out, int E) {
    int o = blockIdx.x * blockDim.x + threadIdx.x;
    if (o > n_out) return;
    int lo = 0, hi = E;
    while (lo < hi) {
        int mid = (lo + hi) >> 1;
        if (oi[mid] < o) lo = mid + 1; else hi = mid;
    }
    start[o] = lo;
}

__global__ __launch_bounds__(256) void k_main(
    const float* __restrict__ x_in, const float* __restrict__ pos_in,
    const float* __restrict__ pos_out, const int* __restrict__ in_index,
    const int* __restrict__ start,
    const float* __restrict__ W1, const float* __restrict__ W2,
    const float* __restrict__ W3, const float* __restrict__ b3,
    float* __restrict__ out, int n_out)
{
    __shared__ float sW3[64 * 64];
    for (int i = threadIdx.x; i < 64 * 64; i += 256) sW3[i] = W3[i];
    __syncthreads();

    const int wave = threadIdx.x >> 6;
    const int lane = threadIdx.x & 63;
    const int o = blockIdx.x * 4 + wave;
    if (o >= n_out) return;

    const int g = lane >> 4;   // edge slot within chunk (0..3)
    const int k = lane & 15;   // h1 channel this lane computes in stage 1

    // W1 column for this lane's k  (W1 is [3][16] row-major)
    const float w1x = W1[0 * 16 + k];
    const float w1y = W1[1 * 16 + k];
    const float w1z = W1[2 * 16 + k];

    // W2 column for this lane's output channel (W2 is [16][64] row-major)
    float w2c[16];
#pragma unroll
    for (int kk = 0; kk < 16; ++kk) w2c[kk] = W2[kk * 64 + lane];

    const float pox = pos_out[o * 3 + 0];
    const float poy = pos_out[o * 3 + 1];
    const float poz = pos_out[o * 3 + 2];

    const int s  = start[o];
    const int se = start[o + 1];
    const int deg = se - s;
    const float inv_deg = 1.0f / (float)(deg > 0 ? deg : 1);

    float agg = 0.0f;  // accumulator for channel `lane`

    for (int base = s; base < se; base += 4) {
        const int e = base + g;
        float h1v = 0.0f;   // zero contribution for invalid edge slots
        float coef = 0.0f;
        if (e < se) {
            const int idx = in_index[e];
            const float px = pos_in[idx * 3 + 0];
            const float py = pos_in[idx * 3 + 1];
            const float pz = pos_in[idx * 3 + 2];
            float pre = (px - pox) * w1x;
            pre = fmaf(py - poy, w1y, pre);
            pre = fmaf(pz - poz, w1z, pre);
            h1v = celu1(pre);
            coef = x_in[idx] * inv_deg;
        }
        // stage 2: for each of the 4 edges, M[j] = celu(h1 . W2[:,j]); agg += coef*M
#pragma unroll
        for (int ee = 0; ee < 4; ++ee) {
            float acc = 0.0f;
#pragma unroll
            for (int kk = 0; kk < 16; ++kk)
                acc = fmaf(bcastf(h1v, ee * 16 + kk), w2c[kk], acc);
            const float m = celu1(acc);
            agg = fmaf(bcastf(coef, ee * 16), m, agg);
        }
    }

    // epilogue: out[o][lane] = sum_c agg_c * W3[c][lane] + b3[lane]
    float oa = b3[lane];
#pragma unroll
    for (int c = 0; c < 64; ++c)
        oa = fmaf(bcastf(agg, c), sW3[c * 64 + lane], oa);

    // nan_to_num(nan=0, posinf=1e6, neginf=-1e6)
    if (isnan(oa)) oa = 0.0f;
    else if (isinf(oa)) oa = (oa > 0.0f) ? 1e6f : -1e6f;

    out[o * 64 + lane] = oa;
}

extern "C" void kernel_launch(void* const* d_in, const int* in_sizes, int n_in,
                              void* d_out, int out_size, void* d_ws, size_t ws_size,
                              hipStream_t stream) {
    const float* x_in      = (const float*)d_in[0];
    const float* pos_in    = (const float*)d_in[1];
    // d_in[2] = batch_in (unused)
    const float* pos_out   = (const float*)d_in[3];
    const int*   in_index  = (const int*)d_in[4];
    const int*   out_index = (const int*)d_in[5];
    const float* W1        = (const float*)d_in[6];
    const float* W2        = (const float*)d_in[7];
    const float* W3        = (const float*)d_in[8];
    const float* b3        = (const float*)d_in[9];
    float* out = (float*)d_out;

    const int n_out = in_sizes[3] / 3;   // pos_out is [N_OUT, 3]
    const int E     = in_sizes[4];

    int* start = (int*)d_ws;             // (n_out + 1) ints

    {
        dim3 b(256), g((n_out + 1 + 255) / 256);
        k_lower_bound<<<g, b, 0, stream>>>(out_index, start, n_out, E);
    }
    {
        dim3 b(256), g((n_out + 3) / 4);
        k_main<<<g, b, 0, stream>>>(x_in, pos_in, pos_out, in_index, start,
                                    W1, W2, W3, b3, out, n_out);
    }
}

// Round 2
// 110.888 us; speedup vs baseline: 1.4082x; 1.4082x over previous
//
#include <hip/hip_runtime.h>
#include <math.h>

// PointConv: N_IN=N_OUT=100000, E=1600000, C_IN=1, C_MID=64, C_OUT=64, POS_DIM=3
//
// Round 2: stage-2 (per-edge 16->64 matvec + celu) moved to MFMA.
//   - one wave per output node; edges processed 16 per MFMA group
//   - B frag: h1 computed directly in fragment layout (lane l -> edge slot l&15,
//     k = 4*(l>>4)+r; k>=16 zero-padded). Verified layout per m162 tr_b16 mapping.
//   - A frag: W2^T tiles (j = jt*16 + (l&15), same k pattern), constant per kernel
//   - D frag: col = lane&15 = edge slot, row = 4*(lane>>4)+r -> lane's own coef
//     multiplies its own D column: no cross-lane traffic in the edge loop
//   - epilogue: DPP row-rotate slot reduction, then readlane-broadcast W3 matvec

typedef __attribute__((ext_vector_type(8))) short short8;
typedef __attribute__((ext_vector_type(4))) float f32x4;

__device__ __forceinline__ float celu1(float x) {
    // celu(x) = max(x, exp(min(x,0)) - 1)
    float m = fminf(x, 0.0f);
    return fmaxf(x, __expf(m) - 1.0f);
}

__device__ __forceinline__ float bcastf(float v, int l) {
    return __int_as_float(__builtin_amdgcn_readlane(__float_as_int(v), l));
}

__device__ __forceinline__ int cvt_pk_bf16(float lo, float hi) {
    int r;
    asm("v_cvt_pk_bf16_f32 %0, %1, %2" : "=v"(r) : "v"(lo), "v"(hi));
    return r;
}

template<int CTRL>
__device__ __forceinline__ float dpp_ror(float v) {
    return __int_as_float(__builtin_amdgcn_update_dpp(
        0, __float_as_int(v), CTRL, 0xF, 0xF, false));
}

// sum across the 16 lanes of each 16-lane row (all lanes get the sum)
__device__ __forceinline__ float rowsum16(float v) {
    v += dpp_ror<0x128>(v);  // row_ror:8
    v += dpp_ror<0x124>(v);  // row_ror:4
    v += dpp_ror<0x122>(v);  // row_ror:2
    v += dpp_ror<0x121>(v);  // row_ror:1
    return v;
}

__global__ void k_lower_bound(const int* __restrict__ oi, int* __restrict__ start,
                              int n_out, int E) {
    int o = blockIdx.x * blockDim.x + threadIdx.x;
    if (o > n_out) return;
    int lo = 0, hi = E;
    while (lo < hi) {
        int mid = (lo + hi) >> 1;
        if (oi[mid] < o) lo = mid + 1; else hi = mid;
    }
    start[o] = lo;
}

__global__ __launch_bounds__(256) void k_main(
    const float* __restrict__ x_in, const float* __restrict__ pos_in,
    const float* __restrict__ pos_out, const int* __restrict__ in_index,
    const int* __restrict__ start,
    const float* __restrict__ W1, const float* __restrict__ W2,
    const float* __restrict__ W3, const float* __restrict__ b3,
    float* __restrict__ out, int n_out)
{
    __shared__ float sW3[64 * 64];
    for (int i = threadIdx.x; i < 64 * 64; i += 256) sW3[i] = W3[i];
    __syncthreads();

    const int wave = threadIdx.x >> 6;
    const int lane = threadIdx.x & 63;
    const int o = blockIdx.x * 4 + wave;
    if (o >= n_out) return;

    const int slot = lane & 15;   // edge slot within 16-edge group / A row within tile
    const int q    = lane >> 4;   // k-quad selector
    const int k0   = q * 4;

    // W1 columns k0..k0+3  (W1 is [3][16] row-major)
    float w1a[4], w1b[4], w1c[4];
#pragma unroll
    for (int r = 0; r < 4; ++r) {
        w1a[r] = W1[0 * 16 + k0 + r];
        w1b[r] = W1[1 * 16 + k0 + r];
        w1c[r] = W1[2 * 16 + k0 + r];
    }

    // A fragments: W2^T tiles. a[jt]: A[m][k] with m = slot -> j = jt*16+slot,
    // k = k0 + (i&3) for i<4; elems 4..7 (k>=16) zero-padded.
    short8 afrag[4];
#pragma unroll
    for (int jt = 0; jt < 4; ++jt) {
        const int j = jt * 16 + slot;
        union { int i[4]; short8 s; } u;
        u.i[0] = cvt_pk_bf16(W2[(k0 + 0) * 64 + j], W2[(k0 + 1) * 64 + j]);
        u.i[1] = cvt_pk_bf16(W2[(k0 + 2) * 64 + j], W2[(k0 + 3) * 64 + j]);
        u.i[2] = 0; u.i[3] = 0;
        afrag[jt] = u.s;
    }

    const float pox = pos_out[o * 3 + 0];
    const float poy = pos_out[o * 3 + 1];
    const float poz = pos_out[o * 3 + 2];

    const int s  = start[o];
    const int se = start[o + 1];
    const int deg = se - s;
    const float inv_deg = 1.0f / (float)(deg > 0 ? deg : 1);

    f32x4 agg[4] = {};                       // accumulators: agg[jt][r] for edge slot = lane&15
    const f32x4 zero4 = {0.f, 0.f, 0.f, 0.f};

    for (int base = s; base < se; base += 16) {
        const int e = base + slot;
        float h[4];
        float coef = 0.0f;
        if (e < se) {
            const int idx = in_index[e];
            const float px = pos_in[idx * 3 + 0] - pox;
            const float py = pos_in[idx * 3 + 1] - poy;
            const float pz = pos_in[idx * 3 + 2] - poz;
#pragma unroll
            for (int r = 0; r < 4; ++r) {
                float pre = px * w1a[r];
                pre = fmaf(py, w1b[r], pre);
                pre = fmaf(pz, w1c[r], pre);
                h[r] = celu1(pre);
            }
            coef = x_in[idx] * inv_deg;
        } else {
            h[0] = h[1] = h[2] = h[3] = 0.0f;
        }

        union { int i[4]; short8 s8; } ub;
        ub.i[0] = cvt_pk_bf16(h[0], h[1]);
        ub.i[1] = cvt_pk_bf16(h[2], h[3]);
        ub.i[2] = 0; ub.i[3] = 0;

#pragma unroll
        for (int jt = 0; jt < 4; ++jt) {
            f32x4 d = __builtin_amdgcn_mfma_f32_16x16x32_bf16(afrag[jt], ub.s8, zero4, 0, 0, 0);
#pragma unroll
            for (int r = 0; r < 4; ++r)
                agg[jt][r] = fmaf(coef, celu1(d[r]), agg[jt][r]);
        }
    }

    // reduce over the 16 edge-slot columns (lanes 0-15 of each q-row)
    float aggv[16];
#pragma unroll
    for (int jt = 0; jt < 4; ++jt)
#pragma unroll
        for (int r = 0; r < 4; ++r)
            aggv[jt * 4 + r] = rowsum16(agg[jt][r]);

    // epilogue: out[o][lane] = b3[lane] + sum_j agg[j] * W3[j][lane]
    // agg[j] (j = jt*16 + 4*qq + r) lives in reg aggv[jt*4+r] of lanes 16*qq..16*qq+15
    float oa = b3[lane];
#pragma unroll
    for (int j = 0; j < 64; ++j) {
        const int jt = j >> 4, rr = j & 15, qq = rr >> 2, r = rr & 3;
        const float av = bcastf(aggv[jt * 4 + r], 16 * qq);
        oa = fmaf(av, sW3[j * 64 + lane], oa);
    }

    if (isnan(oa)) oa = 0.0f;
    else if (isinf(oa)) oa = (oa > 0.0f) ? 1e6f : -1e6f;

    out[o * 64 + lane] = oa;
}

extern "C" void kernel_launch(void* const* d_in, const int* in_sizes, int n_in,
                              void* d_out, int out_size, void* d_ws, size_t ws_size,
                              hipStream_t stream) {
    const float* x_in      = (const float*)d_in[0];
    const float* pos_in    = (const float*)d_in[1];
    // d_in[2] = batch_in (unused)
    const float* pos_out   = (const float*)d_in[3];
    const int*   in_index  = (const int*)d_in[4];
    const int*   out_index = (const int*)d_in[5];
    const float* W1        = (const float*)d_in[6];
    const float* W2        = (const float*)d_in[7];
    const float* W3        = (const float*)d_in[8];
    const float* b3        = (const float*)d_in[9];
    float* out = (float*)d_out;

    const int n_out = in_sizes[3] / 3;   // pos_out is [N_OUT, 3]
    const int E     = in_sizes[4];

    int* start = (int*)d_ws;             // (n_out + 1) ints

    {
        dim3 b(256), g((n_out + 1 + 255) / 256);
        k_lower_bound<<<g, b, 0, stream>>>(out_index, start, n_out, E);
    }
    {
        dim3 b(256), g((n_out + 3) / 4);
        k_main<<<g, b, 0, stream>>>(x_in, pos_in, pos_out, in_index, start,
                                    W1, W2, W3, b3, out, n_out);
    }
}

// Round 4
// 94.115 us; speedup vs baseline: 1.6591x; 1.1782x over previous
//
#include <hip/hip_runtime.h>
#include <math.h>

// PointConv round 4: edge-parallel two-MFMA, scratch minimized to start[] only.
//   k_lower_bound: CSR offsets (out_index sorted) -> start[n_out+1]  (~400 KB ws)
//   k_edges: wave = 4 grid-strided groups of 16 contiguous edges.
//     stage-1 MLP (VALU) -> MFMA1 (h @ W2) -> celu -> MFMA2 with segmentation
//     matrix A2[m][kk]=(rank[kk]==m)?x_in[kk]:0 -> atomic scatter (UNNORMALIZED)
//     into agg (=d_out). deg normalization deferred to k_out (linearity).
//   k_out: in-place (agg/deg) @ W3 + b3 via bf16 MFMA, nan_to_num.
//   W2/W3 fragments packed in-kernel (no prep kernel, no pack scratch).

typedef __attribute__((ext_vector_type(8))) short short8;
typedef __attribute__((ext_vector_type(4))) float f32x4;
typedef __attribute__((ext_vector_type(4))) int   int4v;

union frag_u { int i[4]; short8 v; };

__device__ __forceinline__ float celu1(float x) {
    float m = fminf(x, 0.0f);
    return fmaxf(x, __expf(m) - 1.0f);
}
__device__ __forceinline__ int cvt_pk_bf16(float lo, float hi) {
    int r; asm("v_cvt_pk_bf16_f32 %0, %1, %2" : "=v"(r) : "v"(lo), "v"(hi)); return r;
}

__global__ void k_lower_bound(const int* __restrict__ oi, int* __restrict__ start,
                              int n_out, int E) {
    int o = blockIdx.x * blockDim.x + threadIdx.x;
    if (o > n_out) return;
    int lo = 0, hi = E;
    while (lo < hi) {
        int mid = (lo + hi) >> 1;
        if (oi[mid] < o) lo = mid + 1; else hi = mid;
    }
    start[o] = lo;
}

__global__ __launch_bounds__(256) void k_edges(
    const float* __restrict__ x_in, const float* __restrict__ pos_in,
    const float* __restrict__ pos_out, const int* __restrict__ in_index,
    const int* __restrict__ out_index,
    const float* __restrict__ W1, const float* __restrict__ W2,
    float* __restrict__ agg, int E, int ngroups, int nwaves)
{
    __align__(16) __shared__ int snid_s[4][16];

    const int w = threadIdx.x >> 6, lane = threadIdx.x & 63;
    const int k = lane & 15, q = lane >> 4;

    // B1 = W2 fragments (B[kk=4q+i][n=j=jt*16+(lane&15)]), K upper half zero
    frag_u b1[4];
#pragma unroll
    for (int jt = 0; jt < 4; ++jt) {
        const int j = jt * 16 + k;
        b1[jt].i[0] = cvt_pk_bf16(W2[(4*q+0)*64 + j], W2[(4*q+1)*64 + j]);
        b1[jt].i[1] = cvt_pk_bf16(W2[(4*q+2)*64 + j], W2[(4*q+3)*64 + j]);
        b1[jt].i[2] = 0; b1[jt].i[3] = 0;
    }
    // W1 columns 4q..4q+3 (W1 is [3][16] row-major)
    float w1a[4], w1b[4], w1c[4];
#pragma unroll
    for (int i = 0; i < 4; ++i) {
        w1a[i] = W1[0*16 + 4*q + i];
        w1b[i] = W1[1*16 + 4*q + i];
        w1c[i] = W1[2*16 + 4*q + i];
    }
    const f32x4 zero4 = {0.f, 0.f, 0.f, 0.f};

    for (int g = blockIdx.x * 4 + w; g < ngroups; g += nwaves) {
        const int e = g * 16 + k;
        const bool valid = e < E;
        const int ec = valid ? e : E - 1;

        const int node = out_index[ec];
        const int nprev = (k > 0) ? out_index[ec - 1] : -1;
        const bool head = valid && (k == 0 || node != nprev);
        const unsigned b16 = (unsigned)__ballot(head) & 0xFFFFu;
        const int rank  = __popc(b16 & ((2u << k) - 1)) - 1;
        const int ndist = __popc(b16);

        const int idx = in_index[ec];
        const float coef = valid ? x_in[idx] : 0.0f;   // UNNORMALIZED (deg applied in k_out)
        const float px = pos_in[idx*3+0] - pos_out[node*3+0];
        const float py = pos_in[idx*3+1] - pos_out[node*3+1];
        const float pz = pos_in[idx*3+2] - pos_out[node*3+2];

        float h[4];
#pragma unroll
        for (int i = 0; i < 4; ++i) {
            float pre = px * w1a[i];
            pre = fmaf(py, w1b[i], pre);
            pre = fmaf(pz, w1c[i], pre);
            h[i] = celu1(pre);
        }
        // A1[m=edge slot][kk=4q+i] = h
        frag_u a1;
        a1.i[0] = cvt_pk_bf16(h[0], h[1]);
        a1.i[1] = cvt_pk_bf16(h[2], h[3]);
        a1.i[2] = 0; a1.i[3] = 0;

        if (q == 0 && head) snid_s[w][rank] = node;

        // per-slot coef/rank for slots 4q..4q+3 via shuffles (lanes 0..15 hold all slots)
        const float c0 = __shfl(coef, 4*q+0), c1 = __shfl(coef, 4*q+1),
                    c2 = __shfl(coef, 4*q+2), c3 = __shfl(coef, 4*q+3);
        const int   r0 = __shfl(rank, 4*q+0), r1 = __shfl(rank, 4*q+1),
                    r2 = __shfl(rank, 4*q+2), r3 = __shfl(rank, 4*q+3);

        // A2[m=rank][kk=edge slot] = coef if rank[kk]==m else 0
        frag_u a2;
        a2.i[0] = cvt_pk_bf16(r0 == k ? c0 : 0.0f, r1 == k ? c1 : 0.0f);
        a2.i[1] = cvt_pk_bf16(r2 == k ? c2 : 0.0f, r3 == k ? c3 : 0.0f);
        a2.i[2] = 0; a2.i[3] = 0;

        const int4v n4 = *(const int4v*)&snid_s[w][q * 4];

#pragma unroll
        for (int jt = 0; jt < 4; ++jt) {
            // D1[edge=4q+r][j=jt*16+(lane&15)]
            f32x4 d1 = __builtin_amdgcn_mfma_f32_16x16x32_bf16(a1.v, b1[jt].v, zero4, 0, 0, 0);
            frag_u b2;
            b2.i[0] = cvt_pk_bf16(celu1(d1[0]), celu1(d1[1]));
            b2.i[1] = cvt_pk_bf16(celu1(d1[2]), celu1(d1[3]));
            b2.i[2] = 0; b2.i[3] = 0;
            // D2[rank=4q+r][j]
            f32x4 d2 = __builtin_amdgcn_mfma_f32_16x16x32_bf16(a2.v, b2.v, zero4, 0, 0, 0);
            const int j = jt * 16 + k;
            if (4*q + 0 < ndist) unsafeAtomicAdd(&agg[(long)n4.x * 64 + j], d2[0]);
            if (4*q + 1 < ndist) unsafeAtomicAdd(&agg[(long)n4.y * 64 + j], d2[1]);
            if (4*q + 2 < ndist) unsafeAtomicAdd(&agg[(long)n4.z * 64 + j], d2[2]);
            if (4*q + 3 < ndist) unsafeAtomicAdd(&agg[(long)n4.w * 64 + j], d2[3]);
        }
    }
}

__global__ __launch_bounds__(256) void k_out(
    float* __restrict__ agg, const float* __restrict__ W3,
    const float* __restrict__ b3, const int* __restrict__ start, int n_out)
{
    const int w = threadIdx.x >> 6, lane = threadIdx.x & 63;
    const int s = lane & 15, q = lane >> 4;
    const long base = ((long)blockIdx.x * 4 + w) * 16;
    if (base >= n_out) return;

    // B = W3 fragments, full K=32 chunks (elements 0..3 <-> k=4q+i, 4..7 <-> 16+4q+i)
    frag_u B0[4], B1[4];
#pragma unroll
    for (int jt = 0; jt < 4; ++jt) {
        const int j = jt * 16 + s;
        B0[jt].i[0] = cvt_pk_bf16(W3[( 4*q+0)*64+j], W3[( 4*q+1)*64+j]);
        B0[jt].i[1] = cvt_pk_bf16(W3[( 4*q+2)*64+j], W3[( 4*q+3)*64+j]);
        B0[jt].i[2] = cvt_pk_bf16(W3[(16+4*q+0)*64+j], W3[(16+4*q+1)*64+j]);
        B0[jt].i[3] = cvt_pk_bf16(W3[(16+4*q+2)*64+j], W3[(16+4*q+3)*64+j]);
        B1[jt].i[0] = cvt_pk_bf16(W3[(32+4*q+0)*64+j], W3[(32+4*q+1)*64+j]);
        B1[jt].i[1] = cvt_pk_bf16(W3[(32+4*q+2)*64+j], W3[(32+4*q+3)*64+j]);
        B1[jt].i[2] = cvt_pk_bf16(W3[(48+4*q+0)*64+j], W3[(48+4*q+1)*64+j]);
        B1[jt].i[3] = cvt_pk_bf16(W3[(48+4*q+2)*64+j], W3[(48+4*q+3)*64+j]);
    }

    const long row_i = base + s;
    const long row_c = row_i < n_out ? row_i : n_out - 1;
    const float* row = agg + row_c * 64;
    const int dd = start[row_c + 1] - start[row_c];
    const float invd = 1.0f / (float)(dd > 0 ? dd : 1);

    f32x4 r0 = *(const f32x4*)(row +      4*q);
    f32x4 r1 = *(const f32x4*)(row + 16 + 4*q);
    f32x4 r2 = *(const f32x4*)(row + 32 + 4*q);
    f32x4 r3 = *(const f32x4*)(row + 48 + 4*q);
    r0 *= invd; r1 *= invd; r2 *= invd; r3 *= invd;

    frag_u A0, A1;
    A0.i[0] = cvt_pk_bf16(r0.x, r0.y); A0.i[1] = cvt_pk_bf16(r0.z, r0.w);
    A0.i[2] = cvt_pk_bf16(r1.x, r1.y); A0.i[3] = cvt_pk_bf16(r1.z, r1.w);
    A1.i[0] = cvt_pk_bf16(r2.x, r2.y); A1.i[1] = cvt_pk_bf16(r2.z, r2.w);
    A1.i[2] = cvt_pk_bf16(r3.x, r3.y); A1.i[3] = cvt_pk_bf16(r3.z, r3.w);

    const f32x4 zero4 = {0.f, 0.f, 0.f, 0.f};
#pragma unroll
    for (int jt = 0; jt < 4; ++jt) {
        f32x4 d = __builtin_amdgcn_mfma_f32_16x16x32_bf16(A0.v, B0[jt].v, zero4, 0, 0, 0);
        d = __builtin_amdgcn_mfma_f32_16x16x32_bf16(A1.v, B1[jt].v, d, 0, 0, 0);
        const int j = jt * 16 + s;
        const float bias = b3[j];
#pragma unroll
        for (int r = 0; r < 4; ++r) {
            const long node = base + 4*q + r;
            if (node < n_out) {
                float v = d[r] + bias;
                if (isnan(v)) v = 0.0f;
                else if (isinf(v)) v = (v > 0.0f) ? 1e6f : -1e6f;
                agg[node * 64 + j] = v;
            }
        }
    }
}

extern "C" void kernel_launch(void* const* d_in, const int* in_sizes, int n_in,
                              void* d_out, int out_size, void* d_ws, size_t ws_size,
                              hipStream_t stream) {
    const float* x_in      = (const float*)d_in[0];
    const float* pos_in    = (const float*)d_in[1];
    // d_in[2] = batch_in (unused)
    const float* pos_out   = (const float*)d_in[3];
    const int*   in_index  = (const int*)d_in[4];
    const int*   out_index = (const int*)d_in[5];
    const float* W1        = (const float*)d_in[6];
    const float* W2        = (const float*)d_in[7];
    const float* W3        = (const float*)d_in[8];
    const float* b3        = (const float*)d_in[9];
    float* out = (float*)d_out;

    const int n_out = in_sizes[3] / 3;   // pos_out is [N_OUT, 3]
    const int E     = in_sizes[4];

    int* start = (int*)d_ws;             // (n_out + 1) ints  (~400 KB, round-2-verified size)

    {
        dim3 b(256), g((n_out + 1 + 255) / 256);
        k_lower_bound<<<g, b, 0, stream>>>(out_index, start, n_out, E);
    }

    hipMemsetAsync(d_out, 0, (size_t)n_out * 64 * sizeof(float), stream);

    {
        const int ngroups = (E + 15) / 16;          // 16 edges per group
        const int nblocks = (ngroups + 15) / 16;    // 4 waves/block x 4 groups/wave
        const int nwaves  = nblocks * 4;
        k_edges<<<dim3(nblocks), dim3(256), 0, stream>>>(
            x_in, pos_in, pos_out, in_index, out_index, W1, W2, out, E, ngroups, nwaves);
    }
    {
        const int nblocks = (n_out + 63) / 64;      // 4 waves/block x 16 nodes/wave
        k_out<<<dim3(nblocks), dim3(256), 0, stream>>>(out, W3, b3, start, n_out);
    }
}

// Round 5
// 88.032 us; speedup vs baseline: 1.7738x; 1.0691x over previous
//
#include <hip/hip_runtime.h>
#include <math.h>

// PointConv round 5: edge-parallel two-MFMA, 64 edges/wave scalar phase.
//   k_start: CSR offsets via O(E) coalesced head-scatter (out_index sorted)
//   k_edges: wave = grid-strided windows of 64 contiguous edges.
//     scalar phase 1 edge/lane (coalesced loads, per-lane h[16], one ballot),
//     h transposed via padded LDS into round-4-verified A1 frag layout;
//     per 16-edge quarter: MFMA1 (h @ W2) -> celu -> MFMA2 (segmentation
//     matrix) -> guarded atomic scatter of unnormalized per-node partials.
//   k_out: in-place (agg/deg) @ W3 + b3 via bf16 MFMA, nan_to_num (= round 4).
//   Scratch = start[] only (~400 KB, verified footprint).

typedef __attribute__((ext_vector_type(8))) short short8;
typedef __attribute__((ext_vector_type(4))) float f32x4;
typedef __attribute__((ext_vector_type(4))) int   int4v;
typedef __attribute__((ext_vector_type(2))) int   int2v;

union frag_u { int i[4]; short8 v; };

__device__ __forceinline__ float celu1(float x) {
    float m = fminf(x, 0.0f);
    return fmaxf(x, __expf(m) - 1.0f);
}
__device__ __forceinline__ int cvt_pk_bf16(float lo, float hi) {
    int r; asm("v_cvt_pk_bf16_f32 %0, %1, %2" : "=v"(r) : "v"(lo), "v"(hi)); return r;
}

// start[o] = lower_bound(out_index, o): edge e fills (oi[e-1], oi[e]]
__global__ void k_start(const int* __restrict__ oi, int* __restrict__ start,
                        int n_out, int E) {
    int e = blockIdx.x * blockDim.x + threadIdx.x;
    if (e > E) return;
    int cur  = (e < E) ? oi[e] : n_out;
    int prev = (e > 0) ? oi[e - 1] : -1;
    for (int o = prev + 1; o <= cur; ++o) start[o] = e;
}

__global__ __launch_bounds__(256) void k_edges(
    const float* __restrict__ x_in, const float* __restrict__ pos_in,
    const float* __restrict__ pos_out, const int* __restrict__ in_index,
    const int* __restrict__ out_index,
    const float* __restrict__ W1, const float* __restrict__ W2,
    float* __restrict__ agg, int E, int nwin, int totwaves)
{
    __shared__ int   hbuf [4][64][10];   // padded rows (40B) -> conflict-light reads
    __shared__ float scoef[4][64];
    __shared__ int   srank[4][64];
    __shared__ int   snid [4][64];

    const int wv = threadIdx.x >> 6, lane = threadIdx.x & 63;
    const int kcol = lane & 15, q = lane >> 4;

    // B1 = W2 fragments: B[kk=4q+i][n=j=jt*16+kcol], K upper half zero (round-4 layout)
    frag_u b1[4];
#pragma unroll
    for (int jt = 0; jt < 4; ++jt) {
        const int j = jt * 16 + kcol;
        b1[jt].i[0] = cvt_pk_bf16(W2[(4*q+0)*64 + j], W2[(4*q+1)*64 + j]);
        b1[jt].i[1] = cvt_pk_bf16(W2[(4*q+2)*64 + j], W2[(4*q+3)*64 + j]);
        b1[jt].i[2] = 0; b1[jt].i[3] = 0;
    }
    const f32x4 zero4 = {0.f, 0.f, 0.f, 0.f};

    for (int win = blockIdx.x * 4 + wv; win < nwin; win += totwaves) {
        const int e = win * 64 + lane;
        const bool valid = e < E;
        const int ec = valid ? e : E - 1;

        const int node = out_index[ec];
        const int idx  = in_index[ec];
        const float coef = valid ? x_in[idx] : 0.0f;   // unnormalized; deg in k_out
        const float px = pos_in[idx*3+0] - pos_out[node*3+0];
        const float py = pos_in[idx*3+1] - pos_out[node*3+1];
        const float pz = pos_in[idx*3+2] - pos_out[node*3+2];

        // this lane's edge: all 16 h channels (W1 loads are wave-uniform -> SGPR)
        int hp[8];
#pragma unroll
        for (int c = 0; c < 8; ++c) {
            const float h0 = celu1(fmaf(pz, W1[32 + 2*c],     fmaf(py, W1[16 + 2*c],     px * W1[2*c])));
            const float h1 = celu1(fmaf(pz, W1[32 + 2*c + 1], fmaf(py, W1[16 + 2*c + 1], px * W1[2*c + 1])));
            hp[c] = cvt_pk_bf16(h0, h1);
        }
        *(int4v*)&hbuf[wv][lane][0] = *(const int4v*)&hp[0];
        *(int4v*)&hbuf[wv][lane][4] = *(const int4v*)&hp[4];

        // segmentation: heads forced at each 16-edge quarter boundary (kcol==0)
        const int prevn = __shfl_up(node, 1);
        const bool head = (kcol == 0) || (node != prevn);
        const unsigned long long bal = __ballot(head);
        const unsigned mym = (unsigned)(bal >> (q * 16)) & 0xFFFFu;
        const int rank = __popc(mym & ((2u << kcol) - 1)) - 1;

        scoef[wv][lane] = coef;
        srank[wv][lane] = rank;
        if (head) snid[wv][(lane & 48) + rank] = node;

        int ndq[4];
#pragma unroll
        for (int Q = 0; Q < 4; ++Q) ndq[Q] = __popc((unsigned)(bal >> (Q * 16)) & 0xFFFFu);

#pragma unroll
        for (int Q = 0; Q < 4; ++Q) {
            // A1[m=slot=kcol][kk=4q+i] = h of edge Q*16+kcol (LDS transpose read)
            const int2v a1lo = *(const int2v*)&hbuf[wv][Q*16 + kcol][2*q];
            frag_u a1; a1.i[0] = a1lo.x; a1.i[1] = a1lo.y; a1.i[2] = 0; a1.i[3] = 0;

            const f32x4 c4 = *(const f32x4*)&scoef[wv][Q*16 + 4*q];
            const int4v r4 = *(const int4v*)&srank[wv][Q*16 + 4*q];
            const int4v n4 = *(const int4v*)&snid [wv][Q*16 + 4*q];

            // A2[m=rank=kcol][kk=edge slot 4q+i] = coef if rank[kk]==m else 0
            frag_u a2;
            a2.i[0] = cvt_pk_bf16(r4.x == kcol ? c4.x : 0.0f, r4.y == kcol ? c4.y : 0.0f);
            a2.i[1] = cvt_pk_bf16(r4.z == kcol ? c4.z : 0.0f, r4.w == kcol ? c4.w : 0.0f);
            a2.i[2] = 0; a2.i[3] = 0;

            const int nd = ndq[Q];
            float* p0 = agg + (long)n4.x * 64 + kcol;
            float* p1 = agg + (long)n4.y * 64 + kcol;
            float* p2 = agg + (long)n4.z * 64 + kcol;
            float* p3 = agg + (long)n4.w * 64 + kcol;

#pragma unroll
            for (int jt = 0; jt < 4; ++jt) {
                // D1[edge=4q+r][j=jt*16+kcol]
                f32x4 d1 = __builtin_amdgcn_mfma_f32_16x16x32_bf16(a1.v, b1[jt].v, zero4, 0, 0, 0);
                frag_u b2;
                b2.i[0] = cvt_pk_bf16(celu1(d1[0]), celu1(d1[1]));
                b2.i[1] = cvt_pk_bf16(celu1(d1[2]), celu1(d1[3]));
                b2.i[2] = 0; b2.i[3] = 0;
                // D2[rank=4q+r][j]
                f32x4 d2 = __builtin_amdgcn_mfma_f32_16x16x32_bf16(a2.v, b2.v, zero4, 0, 0, 0);
                if (4*q + 0 < nd) unsafeAtomicAdd(p0 + jt * 16, d2[0]);
                if (4*q + 1 < nd) unsafeAtomicAdd(p1 + jt * 16, d2[1]);
                if (4*q + 2 < nd) unsafeAtomicAdd(p2 + jt * 16, d2[2]);
                if (4*q + 3 < nd) unsafeAtomicAdd(p3 + jt * 16, d2[3]);
            }
        }
    }
}

__global__ __launch_bounds__(256) void k_out(
    float* __restrict__ agg, const float* __restrict__ W3,
    const float* __restrict__ b3, const int* __restrict__ start, int n_out)
{
    const int w = threadIdx.x >> 6, lane = threadIdx.x & 63;
    const int s = lane & 15, q = lane >> 4;
    const long base = ((long)blockIdx.x * 4 + w) * 16;
    if (base >= n_out) return;

    frag_u B0[4], B1[4];
#pragma unroll
    for (int jt = 0; jt < 4; ++jt) {
        const int j = jt * 16 + s;
        B0[jt].i[0] = cvt_pk_bf16(W3[( 4*q+0)*64+j], W3[( 4*q+1)*64+j]);
        B0[jt].i[1] = cvt_pk_bf16(W3[( 4*q+2)*64+j], W3[( 4*q+3)*64+j]);
        B0[jt].i[2] = cvt_pk_bf16(W3[(16+4*q+0)*64+j], W3[(16+4*q+1)*64+j]);
        B0[jt].i[3] = cvt_pk_bf16(W3[(16+4*q+2)*64+j], W3[(16+4*q+3)*64+j]);
        B1[jt].i[0] = cvt_pk_bf16(W3[(32+4*q+0)*64+j], W3[(32+4*q+1)*64+j]);
        B1[jt].i[1] = cvt_pk_bf16(W3[(32+4*q+2)*64+j], W3[(32+4*q+3)*64+j]);
        B1[jt].i[2] = cvt_pk_bf16(W3[(48+4*q+0)*64+j], W3[(48+4*q+1)*64+j]);
        B1[jt].i[3] = cvt_pk_bf16(W3[(48+4*q+2)*64+j], W3[(48+4*q+3)*64+j]);
    }

    const long row_i = base + s;
    const long row_c = row_i < n_out ? row_i : n_out - 1;
    const float* row = agg + row_c * 64;
    const int dd = start[row_c + 1] - start[row_c];
    const float invd = 1.0f / (float)(dd > 0 ? dd : 1);

    f32x4 r0 = *(const f32x4*)(row +      4*q);
    f32x4 r1 = *(const f32x4*)(row + 16 + 4*q);
    f32x4 r2 = *(const f32x4*)(row + 32 + 4*q);
    f32x4 r3 = *(const f32x4*)(row + 48 + 4*q);
    r0 *= invd; r1 *= invd; r2 *= invd; r3 *= invd;

    frag_u A0, A1;
    A0.i[0] = cvt_pk_bf16(r0.x, r0.y); A0.i[1] = cvt_pk_bf16(r0.z, r0.w);
    A0.i[2] = cvt_pk_bf16(r1.x, r1.y); A0.i[3] = cvt_pk_bf16(r1.z, r1.w);
    A1.i[0] = cvt_pk_bf16(r2.x, r2.y); A1.i[1] = cvt_pk_bf16(r2.z, r2.w);
    A1.i[2] = cvt_pk_bf16(r3.x, r3.y); A1.i[3] = cvt_pk_bf16(r3.z, r3.w);

    const f32x4 zero4 = {0.f, 0.f, 0.f, 0.f};
#pragma unroll
    for (int jt = 0; jt < 4; ++jt) {
        f32x4 d = __builtin_amdgcn_mfma_f32_16x16x32_bf16(A0.v, B0[jt].v, zero4, 0, 0, 0);
        d = __builtin_amdgcn_mfma_f32_16x16x32_bf16(A1.v, B1[jt].v, d, 0, 0, 0);
        const int j = jt * 16 + s;
        const float bias = b3[j];
#pragma unroll
        for (int r = 0; r < 4; ++r) {
            const long node = base + 4*q + r;
            if (node < n_out) {
                float v = d[r] + bias;
                if (isnan(v)) v = 0.0f;
                else if (isinf(v)) v = (v > 0.0f) ? 1e6f : -1e6f;
                agg[node * 64 + j] = v;
            }
        }
    }
}

extern "C" void kernel_launch(void* const* d_in, const int* in_sizes, int n_in,
                              void* d_out, int out_size, void* d_ws, size_t ws_size,
                              hipStream_t stream) {
    const float* x_in      = (const float*)d_in[0];
    const float* pos_in    = (const float*)d_in[1];
    // d_in[2] = batch_in (unused)
    const float* pos_out   = (const float*)d_in[3];
    const int*   in_index  = (const int*)d_in[4];
    const int*   out_index = (const int*)d_in[5];
    const float* W1        = (const float*)d_in[6];
    const float* W2        = (const float*)d_in[7];
    const float* W3        = (const float*)d_in[8];
    const float* b3        = (const float*)d_in[9];
    float* out = (float*)d_out;

    const int n_out = in_sizes[3] / 3;   // pos_out is [N_OUT, 3]
    const int E     = in_sizes[4];

    int* start = (int*)d_ws;             // (n_out + 1) ints (verified footprint)

    {
        dim3 b(256), g((E + 1 + 255) / 256);
        k_start<<<g, b, 0, stream>>>(out_index, start, n_out, E);
    }

    hipMemsetAsync(d_out, 0, (size_t)n_out * 64 * sizeof(float), stream);

    {
        const int nwin = (E + 63) / 64;              // 64 edges per window
        const int nblocks = (nwin + 7) / 8;          // 4 waves x 2 windows/wave
        const int totwaves = nblocks * 4;
        k_edges<<<dim3(nblocks), dim3(256), 0, stream>>>(
            x_in, pos_in, pos_out, in_index, out_index, W1, W2, out, E, nwin, totwaves);
    }
    {
        const int nblocks = (n_out + 63) / 64;       // 4 waves x 16 nodes/wave
        k_out<<<dim3(nblocks), dim3(256), 0, stream>>>(out, W3, b3, start, n_out);
    }
}

// Round 6
// 86.762 us; speedup vs baseline: 1.7997x; 1.0146x over previous
//
#include <hip/hip_runtime.h>
#include <math.h>

// PointConv round 6: pipelined edge kernel + ILP-restructured quarters.
//   k_start: CSR offsets via O(E) head-scatter (out_index sorted)
//   k_edges: 2048-block exact-fill grid; wave grid-strides 64-edge windows.
//     2-stage pipeline: window n+1's indices+gathers issued while window n's
//     MFMA/celu phase runs. Per 16-edge quarter: 4x MFMA1 -> 16 celu+cvt ->
//     4x MFMA2 (segmentation matrix) -> guarded atomic scatter (unnormalized).
//   k_out: grid-stride 2 node-tiles/wave, W3 frags + bias hoisted;
//     (agg/deg) @ W3 + b3 via bf16 MFMA, nan_to_num, in-place.
//   Scratch = start[] only (~400 KB verified footprint).

typedef __attribute__((ext_vector_type(8))) short short8;
typedef __attribute__((ext_vector_type(4))) float f32x4;
typedef __attribute__((ext_vector_type(4))) int   int4v;
typedef __attribute__((ext_vector_type(2))) int   int2v;

union frag_u { int i[4]; short8 v; };

__device__ __forceinline__ float celu1(float x) {
    float m = fminf(x, 0.0f);
    return fmaxf(x, __expf(m) - 1.0f);
}
__device__ __forceinline__ int cvt_pk_bf16(float lo, float hi) {
    int r; asm("v_cvt_pk_bf16_f32 %0, %1, %2" : "=v"(r) : "v"(lo), "v"(hi)); return r;
}

__global__ void k_start(const int* __restrict__ oi, int* __restrict__ start,
                        int n_out, int E) {
    int e = blockIdx.x * blockDim.x + threadIdx.x;
    if (e > E) return;
    int cur  = (e < E) ? oi[e] : n_out;
    int prev = (e > 0) ? oi[e - 1] : -1;
    for (int o = prev + 1; o <= cur; ++o) start[o] = e;
}

__global__ __launch_bounds__(256) void k_edges(
    const float* __restrict__ x_in, const float* __restrict__ pos_in,
    const float* __restrict__ pos_out, const int* __restrict__ in_index,
    const int* __restrict__ out_index,
    const float* __restrict__ W1, const float* __restrict__ W2,
    float* __restrict__ agg, int E, int nwin, int totwaves)
{
    __shared__ int   hbuf [4][64][10];
    __shared__ float scoef[4][64];
    __shared__ int   srank[4][64];
    __shared__ int   snid [4][64];

    const int wv = threadIdx.x >> 6, lane = threadIdx.x & 63;
    const int kcol = lane & 15, q = lane >> 4;

    // B1 = W2 fragments: B[kk=4q+i][n=j=jt*16+kcol], K upper half zero
    frag_u b1[4];
#pragma unroll
    for (int jt = 0; jt < 4; ++jt) {
        const int j = jt * 16 + kcol;
        b1[jt].i[0] = cvt_pk_bf16(W2[(4*q+0)*64 + j], W2[(4*q+1)*64 + j]);
        b1[jt].i[1] = cvt_pk_bf16(W2[(4*q+2)*64 + j], W2[(4*q+3)*64 + j]);
        b1[jt].i[2] = 0; b1[jt].i[3] = 0;
    }
    const f32x4 zero4 = {0.f, 0.f, 0.f, 0.f};

    int win = blockIdx.x * 4 + wv;

    // pipeline registers (window `win`)
    int node = 0, idx = 0; float xv = 0.f;
    float pix = 0.f, piy = 0.f, piz = 0.f, pox = 0.f, poy = 0.f, poz = 0.f;
    bool valid = false;

    if (win < nwin) {
        const int e = win * 64 + lane;
        valid = e < E;
        const int ec = valid ? e : E - 1;
        node = out_index[ec]; idx = in_index[ec];
        xv = x_in[idx];
        pix = pos_in[idx*3+0]; piy = pos_in[idx*3+1]; piz = pos_in[idx*3+2];
        pox = pos_out[node*3+0]; poy = pos_out[node*3+1]; poz = pos_out[node*3+2];
    }

    while (win < nwin) {
        // ---- stage A: segmentation + h + LDS tables for current window ----
        const float coef = valid ? xv : 0.0f;       // unnormalized; deg in k_out
        const float px = pix - pox, py = piy - poy, pz = piz - poz;

        const int prevn = __shfl_up(node, 1);
        const bool head = (kcol == 0) || (node != prevn);
        const unsigned long long bal = __ballot(head);
        const unsigned mym = (unsigned)(bal >> (q * 16)) & 0xFFFFu;
        const int rank = __popc(mym & ((2u << kcol) - 1)) - 1;

        scoef[wv][lane] = coef;
        srank[wv][lane] = rank;
        if (head) snid[wv][(lane & 48) + rank] = node;

        int hp[8];
#pragma unroll
        for (int c = 0; c < 8; ++c) {
            const float h0 = celu1(fmaf(pz, W1[32 + 2*c],     fmaf(py, W1[16 + 2*c],     px * W1[2*c])));
            const float h1 = celu1(fmaf(pz, W1[32 + 2*c + 1], fmaf(py, W1[16 + 2*c + 1], px * W1[2*c + 1])));
            hp[c] = cvt_pk_bf16(h0, h1);
        }
        *(int4v*)&hbuf[wv][lane][0] = *(const int4v*)&hp[0];
        *(int4v*)&hbuf[wv][lane][4] = *(const int4v*)&hp[4];

        // ---- stage B: prefetch window win+totwaves (hides gather latency) ----
        const int win2 = win + totwaves;
        int node2 = 0, idx2 = 0; float xv2 = 0.f;
        float pix2 = 0.f, piy2 = 0.f, piz2 = 0.f, pox2 = 0.f, poy2 = 0.f, poz2 = 0.f;
        bool valid2 = false;
        if (win2 < nwin) {
            const int e2 = win2 * 64 + lane;
            valid2 = e2 < E;
            const int ec2 = valid2 ? e2 : E - 1;
            node2 = out_index[ec2]; idx2 = in_index[ec2];
            xv2 = x_in[idx2];
            pix2 = pos_in[idx2*3+0]; piy2 = pos_in[idx2*3+1]; piz2 = pos_in[idx2*3+2];
            pox2 = pos_out[node2*3+0]; poy2 = pos_out[node2*3+1]; poz2 = pos_out[node2*3+2];
        }

        // ---- stage C: per-quarter MFMA compute ----
#pragma unroll
        for (int Q = 0; Q < 4; ++Q) {
            const int nd = __popc((unsigned)(bal >> (Q * 16)) & 0xFFFFu);

            // A1[m=slot=kcol][kk=4q+i] = h of edge Q*16+kcol
            const int2v a1lo = *(const int2v*)&hbuf[wv][Q*16 + kcol][2*q];
            frag_u a1; a1.i[0] = a1lo.x; a1.i[1] = a1lo.y; a1.i[2] = 0; a1.i[3] = 0;

            const f32x4 c4 = *(const f32x4*)&scoef[wv][Q*16 + 4*q];
            const int4v r4 = *(const int4v*)&srank[wv][Q*16 + 4*q];
            const int4v n4 = *(const int4v*)&snid [wv][Q*16 + 4*q];

            // A2[m=rank=kcol][kk=slot 4q+i] = coef if rank[kk]==m else 0
            frag_u a2;
            a2.i[0] = cvt_pk_bf16(r4.x == kcol ? c4.x : 0.0f, r4.y == kcol ? c4.y : 0.0f);
            a2.i[1] = cvt_pk_bf16(r4.z == kcol ? c4.z : 0.0f, r4.w == kcol ? c4.w : 0.0f);
            a2.i[2] = 0; a2.i[3] = 0;

            // 4 independent d1 chains
            f32x4 d1[4];
#pragma unroll
            for (int jt = 0; jt < 4; ++jt)
                d1[jt] = __builtin_amdgcn_mfma_f32_16x16x32_bf16(a1.v, b1[jt].v, zero4, 0, 0, 0);

            frag_u b2[4];
#pragma unroll
            for (int jt = 0; jt < 4; ++jt) {
                b2[jt].i[0] = cvt_pk_bf16(celu1(d1[jt][0]), celu1(d1[jt][1]));
                b2[jt].i[1] = cvt_pk_bf16(celu1(d1[jt][2]), celu1(d1[jt][3]));
                b2[jt].i[2] = 0; b2[jt].i[3] = 0;
            }

            f32x4 d2[4];
#pragma unroll
            for (int jt = 0; jt < 4; ++jt)
                d2[jt] = __builtin_amdgcn_mfma_f32_16x16x32_bf16(a2.v, b2[jt].v, zero4, 0, 0, 0);

            float* p0 = agg + (long)n4.x * 64 + kcol;
            float* p1 = agg + (long)n4.y * 64 + kcol;
            float* p2 = agg + (long)n4.z * 64 + kcol;
            float* p3 = agg + (long)n4.w * 64 + kcol;
#pragma unroll
            for (int jt = 0; jt < 4; ++jt) {
                if (4*q + 0 < nd) unsafeAtomicAdd(p0 + jt * 16, d2[jt][0]);
                if (4*q + 1 < nd) unsafeAtomicAdd(p1 + jt * 16, d2[jt][1]);
                if (4*q + 2 < nd) unsafeAtomicAdd(p2 + jt * 16, d2[jt][2]);
                if (4*q + 3 < nd) unsafeAtomicAdd(p3 + jt * 16, d2[jt][3]);
            }
        }

        // ---- rotate pipeline ----
        node = node2; idx = idx2; xv = xv2;
        pix = pix2; piy = piy2; piz = piz2;
        pox = pox2; poy = poy2; poz = poz2;
        valid = valid2; win = win2;
    }
}

__global__ __launch_bounds__(256) void k_out(
    float* __restrict__ agg, const float* __restrict__ W3,
    const float* __restrict__ b3, const int* __restrict__ start,
    int n_out, int ntiles, int totwaves)
{
    const int wv = threadIdx.x >> 6, lane = threadIdx.x & 63;
    const int s = lane & 15, q = lane >> 4;

    // hoisted: W3 fragments + bias (reused across tiles)
    frag_u B0[4], B1[4];
    float bias[4];
#pragma unroll
    for (int jt = 0; jt < 4; ++jt) {
        const int j = jt * 16 + s;
        bias[jt] = b3[j];
        B0[jt].i[0] = cvt_pk_bf16(W3[( 4*q+0)*64+j], W3[( 4*q+1)*64+j]);
        B0[jt].i[1] = cvt_pk_bf16(W3[( 4*q+2)*64+j], W3[( 4*q+3)*64+j]);
        B0[jt].i[2] = cvt_pk_bf16(W3[(16+4*q+0)*64+j], W3[(16+4*q+1)*64+j]);
        B0[jt].i[3] = cvt_pk_bf16(W3[(16+4*q+2)*64+j], W3[(16+4*q+3)*64+j]);
        B1[jt].i[0] = cvt_pk_bf16(W3[(32+4*q+0)*64+j], W3[(32+4*q+1)*64+j]);
        B1[jt].i[1] = cvt_pk_bf16(W3[(32+4*q+2)*64+j], W3[(32+4*q+3)*64+j]);
        B1[jt].i[2] = cvt_pk_bf16(W3[(48+4*q+0)*64+j], W3[(48+4*q+1)*64+j]);
        B1[jt].i[3] = cvt_pk_bf16(W3[(48+4*q+2)*64+j], W3[(48+4*q+3)*64+j]);
    }
    const f32x4 zero4 = {0.f, 0.f, 0.f, 0.f};

    for (int tile = blockIdx.x * 4 + wv; tile < ntiles; tile += totwaves) {
        const long base = (long)tile * 16;

        const long row_i = base + s;
        const long row_c = row_i < n_out ? row_i : n_out - 1;
        const float* row = agg + row_c * 64;
        const int dd = start[row_c + 1] - start[row_c];
        const float invd = 1.0f / (float)(dd > 0 ? dd : 1);

        f32x4 r0 = *(const f32x4*)(row +      4*q);
        f32x4 r1 = *(const f32x4*)(row + 16 + 4*q);
        f32x4 r2 = *(const f32x4*)(row + 32 + 4*q);
        f32x4 r3 = *(const f32x4*)(row + 48 + 4*q);
        r0 *= invd; r1 *= invd; r2 *= invd; r3 *= invd;

        frag_u A0, A1;
        A0.i[0] = cvt_pk_bf16(r0.x, r0.y); A0.i[1] = cvt_pk_bf16(r0.z, r0.w);
        A0.i[2] = cvt_pk_bf16(r1.x, r1.y); A0.i[3] = cvt_pk_bf16(r1.z, r1.w);
        A1.i[0] = cvt_pk_bf16(r2.x, r2.y); A1.i[1] = cvt_pk_bf16(r2.z, r2.w);
        A1.i[2] = cvt_pk_bf16(r3.x, r3.y); A1.i[3] = cvt_pk_bf16(r3.z, r3.w);

#pragma unroll
        for (int jt = 0; jt < 4; ++jt) {
            f32x4 d = __builtin_amdgcn_mfma_f32_16x16x32_bf16(A0.v, B0[jt].v, zero4, 0, 0, 0);
            d = __builtin_amdgcn_mfma_f32_16x16x32_bf16(A1.v, B1[jt].v, d, 0, 0, 0);
            const int j = jt * 16 + s;
#pragma unroll
            for (int r = 0; r < 4; ++r) {
                const long nodei = base + 4*q + r;
                if (nodei < n_out) {
                    float v = d[r] + bias[jt];
                    if (isnan(v)) v = 0.0f;
                    else if (isinf(v)) v = (v > 0.0f) ? 1e6f : -1e6f;
                    agg[nodei * 64 + j] = v;
                }
            }
        }
    }
}

extern "C" void kernel_launch(void* const* d_in, const int* in_sizes, int n_in,
                              void* d_out, int out_size, void* d_ws, size_t ws_size,
                              hipStream_t stream) {
    const float* x_in      = (const float*)d_in[0];
    const float* pos_in    = (const float*)d_in[1];
    // d_in[2] = batch_in (unused)
    const float* pos_out   = (const float*)d_in[3];
    const int*   in_index  = (const int*)d_in[4];
    const int*   out_index = (const int*)d_in[5];
    const float* W1        = (const float*)d_in[6];
    const float* W2        = (const float*)d_in[7];
    const float* W3        = (const float*)d_in[8];
    const float* b3        = (const float*)d_in[9];
    float* out = (float*)d_out;

    const int n_out = in_sizes[3] / 3;   // pos_out is [N_OUT, 3]
    const int E     = in_sizes[4];

    int* start = (int*)d_ws;             // (n_out + 1) ints (verified footprint)

    {
        dim3 b(256), g((E + 1 + 255) / 256);
        k_start<<<g, b, 0, stream>>>(out_index, start, n_out, E);
    }

    hipMemsetAsync(d_out, 0, (size_t)n_out * 64 * sizeof(float), stream);

    {
        const int nwin = (E + 63) / 64;                 // 64 edges per window
        int nblocks = (nwin + 3) / 4;
        if (nblocks > 2048) nblocks = 2048;             // exact-fill grid, grid-stride
        const int totwaves = nblocks * 4;
        k_edges<<<dim3(nblocks), dim3(256), 0, stream>>>(
            x_in, pos_in, pos_out, in_index, out_index, W1, W2, out, E, nwin, totwaves);
    }
    {
        const int ntiles = (n_out + 15) / 16;           // 16 nodes per tile
        int nblocks = (ntiles + 7) / 8;                 // ~2 tiles per wave
        const int totwaves = nblocks * 4;
        k_out<<<dim3(nblocks), dim3(256), 0, stream>>>(
            out, W3, b3, start, n_out, ntiles, totwaves);
    }
}

// Round 7
// 84.210 us; speedup vs baseline: 1.8543x; 1.0303x over previous
//
#include <hip/hip_runtime.h>
#include <math.h>

// PointConv round 7: 32-slot MFMA2 packing + indices-only prefetch.
//   k_start: CSR offsets via O(E) head-scatter (out_index sorted)
//   k_edges: wave grid-strides 64-edge windows (no deep pipeline — r6 regression
//     reverted; only next window's indices prefetched).
//     Per window: per-lane h[16] -> LDS transpose; segmentation over 32-edge
//     HALVES (ballot/rank); per half: 8x MFMA1 (two 16-edge quarters) ->
//     celu -> ONE A2 (full K=32: elems 0-3 = slots 0-15, elems 4-7 = slots
//     16-31, mapping verified by k_out's full-K fragments) -> 4x MFMA2 ->
//     guarded atomic scatter (unnormalized; deg in k_out). Rare nd>16 handled
//     by wave-uniform high-rank pass.
//   k_out: grid-stride; (agg/deg) @ W3 + b3 via bf16 MFMA, nan_to_num, in-place.
//   Scratch = start[] only (~400 KB verified footprint).

typedef __attribute__((ext_vector_type(8))) short short8;
typedef __attribute__((ext_vector_type(4))) float f32x4;
typedef __attribute__((ext_vector_type(4))) int   int4v;
typedef __attribute__((ext_vector_type(2))) int   int2v;

union frag_u { int i[4]; short8 v; };

__device__ __forceinline__ float celu1(float x) {
    float m = fminf(x, 0.0f);
    return fmaxf(x, __expf(m) - 1.0f);
}
__device__ __forceinline__ int cvt_pk_bf16(float lo, float hi) {
    int r; asm("v_cvt_pk_bf16_f32 %0, %1, %2" : "=v"(r) : "v"(lo), "v"(hi)); return r;
}

__global__ void k_start(const int* __restrict__ oi, int* __restrict__ start,
                        int n_out, int E) {
    int e = blockIdx.x * blockDim.x + threadIdx.x;
    if (e > E) return;
    int cur  = (e < E) ? oi[e] : n_out;
    int prev = (e > 0) ? oi[e - 1] : -1;
    for (int o = prev + 1; o <= cur; ++o) start[o] = e;
}

__global__ __launch_bounds__(256, 6) void k_edges(
    const float* __restrict__ x_in, const float* __restrict__ pos_in,
    const float* __restrict__ pos_out, const int* __restrict__ in_index,
    const int* __restrict__ out_index,
    const float* __restrict__ W1, const float* __restrict__ W2,
    float* __restrict__ agg, int E, int nwin, int totwaves)
{
    __shared__ int   hbuf [4][64][10];
    __shared__ float scoef[4][64];
    __shared__ int   srank[4][64];
    __shared__ int   snid [4][64];

    const int wv = threadIdx.x >> 6, lane = threadIdx.x & 63;
    const int kcol = lane & 15, q = lane >> 4;
    const int half = lane >> 5;            // which 32-edge half this lane's edge is in
    const int slot32 = lane & 31;          // slot within the half

    // B1 = W2 fragments: B[kk=4q+i][n=j=jt*16+kcol], K upper half zero
    frag_u b1[4];
#pragma unroll
    for (int jt = 0; jt < 4; ++jt) {
        const int j = jt * 16 + kcol;
        b1[jt].i[0] = cvt_pk_bf16(W2[(4*q+0)*64 + j], W2[(4*q+1)*64 + j]);
        b1[jt].i[1] = cvt_pk_bf16(W2[(4*q+2)*64 + j], W2[(4*q+3)*64 + j]);
        b1[jt].i[2] = 0; b1[jt].i[3] = 0;
    }
    const f32x4 zero4 = {0.f, 0.f, 0.f, 0.f};

    int win = blockIdx.x * 4 + wv;
    int node = 0, idx = 0;
    if (win < nwin) {
        const int e = win * 64 + lane;
        const int ec = (e < E) ? e : E - 1;
        node = out_index[ec];
        idx  = in_index[ec];
    }

    while (win < nwin) {
        const int e = win * 64 + lane;
        const bool valid = e < E;

        // ---- gathers for this window (idx/node already in registers) ----
        const float xv  = x_in[idx];
        const float pix = pos_in[idx*3+0], piy = pos_in[idx*3+1], piz = pos_in[idx*3+2];
        const float pox = pos_out[node*3+0], poy = pos_out[node*3+1], poz = pos_out[node*3+2];

        // ---- prefetch next window's indices (hides index-stream HBM miss) ----
        const int win_n = win + totwaves;
        int node_n = node, idx_n = idx;
        if (win_n < nwin) {
            const int e2 = win_n * 64 + lane;
            const int ec2 = (e2 < E) ? e2 : E - 1;
            node_n = out_index[ec2];
            idx_n  = in_index[ec2];
        }

        // ---- segmentation over 32-edge halves ----
        const float coef = valid ? xv : 0.0f;      // unnormalized; deg in k_out
        const int prevn = __shfl_up(node, 1);
        const bool head = (slot32 == 0) || (node != prevn);
        const unsigned long long bal = __ballot(head);
        const unsigned mym = (unsigned)(bal >> (half * 32));
        const int rank = __popc(mym & ((2u << slot32) - 1)) - 1;
        const int nd0 = __popc((unsigned)bal);
        const int nd1 = __popc((unsigned)(bal >> 32));

        scoef[wv][lane] = coef;
        srank[wv][lane] = rank;
        if (head) snid[wv][(lane & 32) + rank] = node;

        // ---- per-lane h[16] for its own edge ----
        const float px = pix - pox, py = piy - poy, pz = piz - poz;
        int hp[8];
#pragma unroll
        for (int c = 0; c < 8; ++c) {
            const float h0 = celu1(fmaf(pz, W1[32 + 2*c],     fmaf(py, W1[16 + 2*c],     px * W1[2*c])));
            const float h1 = celu1(fmaf(pz, W1[32 + 2*c + 1], fmaf(py, W1[16 + 2*c + 1], px * W1[2*c + 1])));
            hp[c] = cvt_pk_bf16(h0, h1);
        }
        *(int4v*)&hbuf[wv][lane][0] = *(const int4v*)&hp[0];
        *(int4v*)&hbuf[wv][lane][4] = *(const int4v*)&hp[4];

        __builtin_amdgcn_s_setprio(1);

        // ---- per 32-edge half: 8x MFMA1 -> celu -> 1x A2(K=32) -> 4x MFMA2 -> scatter ----
#pragma unroll
        for (int h2 = 0; h2 < 2; ++h2) {
            const int sbase = h2 * 32;
            const int nd = h2 ? nd1 : nd0;

            // A2: elems 0-3 = slots sbase+4q+i (quarter A), elems 4-7 = slots sbase+16+4q+i (quarter B)
            const f32x4 cLo = *(const f32x4*)&scoef[wv][sbase + 4*q];
            const int4v rLo = *(const int4v*)&srank[wv][sbase + 4*q];
            const f32x4 cHi = *(const f32x4*)&scoef[wv][sbase + 16 + 4*q];
            const int4v rHi = *(const int4v*)&srank[wv][sbase + 16 + 4*q];
            const int4v n4  = *(const int4v*)&snid [wv][sbase + 4*q];

            frag_u a2;
            a2.i[0] = cvt_pk_bf16(rLo.x == kcol ? cLo.x : 0.0f, rLo.y == kcol ? cLo.y : 0.0f);
            a2.i[1] = cvt_pk_bf16(rLo.z == kcol ? cLo.z : 0.0f, rLo.w == kcol ? cLo.w : 0.0f);
            a2.i[2] = cvt_pk_bf16(rHi.x == kcol ? cHi.x : 0.0f, rHi.y == kcol ? cHi.y : 0.0f);
            a2.i[3] = cvt_pk_bf16(rHi.z == kcol ? cHi.z : 0.0f, rHi.w == kcol ? cHi.w : 0.0f);

            // A1 frags for the two quarters of this half
            const int2v aA = *(const int2v*)&hbuf[wv][sbase + kcol][2*q];
            const int2v aB = *(const int2v*)&hbuf[wv][sbase + 16 + kcol][2*q];
            frag_u a1A; a1A.i[0] = aA.x; a1A.i[1] = aA.y; a1A.i[2] = 0; a1A.i[3] = 0;
            frag_u a1B; a1B.i[0] = aB.x; a1B.i[1] = aB.y; a1B.i[2] = 0; a1B.i[3] = 0;

            const int ndLo = nd < 16 ? nd : 16;
            float* p0 = agg + (long)n4.x * 64 + kcol;
            float* p1 = agg + (long)n4.y * 64 + kcol;
            float* p2 = agg + (long)n4.z * 64 + kcol;
            float* p3 = agg + (long)n4.w * 64 + kcol;

#pragma unroll
            for (int jt = 0; jt < 4; ++jt) {
                f32x4 d1A = __builtin_amdgcn_mfma_f32_16x16x32_bf16(a1A.v, b1[jt].v, zero4, 0, 0, 0);
                f32x4 d1B = __builtin_amdgcn_mfma_f32_16x16x32_bf16(a1B.v, b1[jt].v, zero4, 0, 0, 0);
                frag_u b2;
                b2.i[0] = cvt_pk_bf16(celu1(d1A[0]), celu1(d1A[1]));
                b2.i[1] = cvt_pk_bf16(celu1(d1A[2]), celu1(d1A[3]));
                b2.i[2] = cvt_pk_bf16(celu1(d1B[0]), celu1(d1B[1]));
                b2.i[3] = cvt_pk_bf16(celu1(d1B[2]), celu1(d1B[3]));
                f32x4 d2 = __builtin_amdgcn_mfma_f32_16x16x32_bf16(a2.v, b2.v, zero4, 0, 0, 0);
                if (4*q + 0 < ndLo) unsafeAtomicAdd(p0 + jt * 16, d2[0]);
                if (4*q + 1 < ndLo) unsafeAtomicAdd(p1 + jt * 16, d2[1]);
                if (4*q + 2 < ndLo) unsafeAtomicAdd(p2 + jt * 16, d2[2]);
                if (4*q + 3 < ndLo) unsafeAtomicAdd(p3 + jt * 16, d2[3]);

                if (nd > 16) {   // rare: >16 distinct nodes in 32 sorted edges
                    frag_u a2h;
                    a2h.i[0] = cvt_pk_bf16(rLo.x - 16 == kcol ? cLo.x : 0.0f, rLo.y - 16 == kcol ? cLo.y : 0.0f);
                    a2h.i[1] = cvt_pk_bf16(rLo.z - 16 == kcol ? cLo.z : 0.0f, rLo.w - 16 == kcol ? cLo.w : 0.0f);
                    a2h.i[2] = cvt_pk_bf16(rHi.x - 16 == kcol ? cHi.x : 0.0f, rHi.y - 16 == kcol ? cHi.y : 0.0f);
                    a2h.i[3] = cvt_pk_bf16(rHi.z - 16 == kcol ? cHi.z : 0.0f, rHi.w - 16 == kcol ? cHi.w : 0.0f);
                    f32x4 d2h = __builtin_amdgcn_mfma_f32_16x16x32_bf16(a2h.v, b2.v, zero4, 0, 0, 0);
                    const int4v n4h = *(const int4v*)&snid[wv][sbase + 16 + 4*q];
                    const int ndHi = nd - 16;
                    if (4*q + 0 < ndHi) unsafeAtomicAdd(agg + (long)n4h.x * 64 + kcol + jt * 16, d2h[0]);
                    if (4*q + 1 < ndHi) unsafeAtomicAdd(agg + (long)n4h.y * 64 + kcol + jt * 16, d2h[1]);
                    if (4*q + 2 < ndHi) unsafeAtomicAdd(agg + (long)n4h.z * 64 + kcol + jt * 16, d2h[2]);
                    if (4*q + 3 < ndHi) unsafeAtomicAdd(agg + (long)n4h.w * 64 + kcol + jt * 16, d2h[3]);
                }
            }
        }
        __builtin_amdgcn_s_setprio(0);

        node = node_n; idx = idx_n; win = win_n;
    }
}

__global__ __launch_bounds__(256) void k_out(
    float* __restrict__ agg, const float* __restrict__ W3,
    const float* __restrict__ b3, const int* __restrict__ start,
    int n_out, int ntiles, int totwaves)
{
    const int wv = threadIdx.x >> 6, lane = threadIdx.x & 63;
    const int s = lane & 15, q = lane >> 4;

    frag_u B0[4], B1[4];
    float bias[4];
#pragma unroll
    for (int jt = 0; jt < 4; ++jt) {
        const int j = jt * 16 + s;
        bias[jt] = b3[j];
        B0[jt].i[0] = cvt_pk_bf16(W3[( 4*q+0)*64+j], W3[( 4*q+1)*64+j]);
        B0[jt].i[1] = cvt_pk_bf16(W3[( 4*q+2)*64+j], W3[( 4*q+3)*64+j]);
        B0[jt].i[2] = cvt_pk_bf16(W3[(16+4*q+0)*64+j], W3[(16+4*q+1)*64+j]);
        B0[jt].i[3] = cvt_pk_bf16(W3[(16+4*q+2)*64+j], W3[(16+4*q+3)*64+j]);
        B1[jt].i[0] = cvt_pk_bf16(W3[(32+4*q+0)*64+j], W3[(32+4*q+1)*64+j]);
        B1[jt].i[1] = cvt_pk_bf16(W3[(32+4*q+2)*64+j], W3[(32+4*q+3)*64+j]);
        B1[jt].i[2] = cvt_pk_bf16(W3[(48+4*q+0)*64+j], W3[(48+4*q+1)*64+j]);
        B1[jt].i[3] = cvt_pk_bf16(W3[(48+4*q+2)*64+j], W3[(48+4*q+3)*64+j]);
    }
    const f32x4 zero4 = {0.f, 0.f, 0.f, 0.f};

    for (int tile = blockIdx.x * 4 + wv; tile < ntiles; tile += totwaves) {
        const long base = (long)tile * 16;

        const long row_i = base + s;
        const long row_c = row_i < n_out ? row_i : n_out - 1;
        const float* row = agg + row_c * 64;
        const int dd = start[row_c + 1] - start[row_c];
        const float invd = 1.0f / (float)(dd > 0 ? dd : 1);

        f32x4 r0 = *(const f32x4*)(row +      4*q);
        f32x4 r1 = *(const f32x4*)(row + 16 + 4*q);
        f32x4 r2 = *(const f32x4*)(row + 32 + 4*q);
        f32x4 r3 = *(const f32x4*)(row + 48 + 4*q);
        r0 *= invd; r1 *= invd; r2 *= invd; r3 *= invd;

        frag_u A0, A1;
        A0.i[0] = cvt_pk_bf16(r0.x, r0.y); A0.i[1] = cvt_pk_bf16(r0.z, r0.w);
        A0.i[2] = cvt_pk_bf16(r1.x, r1.y); A0.i[3] = cvt_pk_bf16(r1.z, r1.w);
        A1.i[0] = cvt_pk_bf16(r2.x, r2.y); A1.i[1] = cvt_pk_bf16(r2.z, r2.w);
        A1.i[2] = cvt_pk_bf16(r3.x, r3.y); A1.i[3] = cvt_pk_bf16(r3.z, r3.w);

#pragma unroll
        for (int jt = 0; jt < 4; ++jt) {
            f32x4 d = __builtin_amdgcn_mfma_f32_16x16x32_bf16(A0.v, B0[jt].v, zero4, 0, 0, 0);
            d = __builtin_amdgcn_mfma_f32_16x16x32_bf16(A1.v, B1[jt].v, d, 0, 0, 0);
            const int j = jt * 16 + s;
#pragma unroll
            for (int r = 0; r < 4; ++r) {
                const long nodei = base + 4*q + r;
                if (nodei < n_out) {
                    float v = d[r] + bias[jt];
                    if (isnan(v)) v = 0.0f;
                    else if (isinf(v)) v = (v > 0.0f) ? 1e6f : -1e6f;
                    agg[nodei * 64 + j] = v;
                }
            }
        }
    }
}

extern "C" void kernel_launch(void* const* d_in, const int* in_sizes, int n_in,
                              void* d_out, int out_size, void* d_ws, size_t ws_size,
                              hipStream_t stream) {
    const float* x_in      = (const float*)d_in[0];
    const float* pos_in    = (const float*)d_in[1];
    // d_in[2] = batch_in (unused)
    const float* pos_out   = (const float*)d_in[3];
    const int*   in_index  = (const int*)d_in[4];
    const int*   out_index = (const int*)d_in[5];
    const float* W1        = (const float*)d_in[6];
    const float* W2        = (const float*)d_in[7];
    const float* W3        = (const float*)d_in[8];
    const float* b3        = (const float*)d_in[9];
    float* out = (float*)d_out;

    const int n_out = in_sizes[3] / 3;   // pos_out is [N_OUT, 3]
    const int E     = in_sizes[4];

    int* start = (int*)d_ws;             // (n_out + 1) ints (verified footprint)

    {
        dim3 b(256), g((E + 1 + 255) / 256);
        k_start<<<g, b, 0, stream>>>(out_index, start, n_out, E);
    }

    hipMemsetAsync(d_out, 0, (size_t)n_out * 64 * sizeof(float), stream);

    {
        const int nwin = (E + 63) / 64;                 // 64 edges per window
        int nblocks = (nwin + 3) / 4;
        if (nblocks > 2048) nblocks = 2048;             // full residency, grid-stride
        const int totwaves = nblocks * 4;
        k_edges<<<dim3(nblocks), dim3(256), 0, stream>>>(
            x_in, pos_in, pos_out, in_index, out_index, W1, W2, out, E, nwin, totwaves);
    }
    {
        const int ntiles = (n_out + 15) / 16;           // 16 nodes per tile
        int nblocks = (ntiles + 7) / 8;                 // ~2 tiles per wave
        const int totwaves = nblocks * 4;
        k_out<<<dim3(nblocks), dim3(256), 0, stream>>>(
            out, W3, b3, start, n_out, ntiles, totwaves);
    }
}